// Round 2
// baseline (155.094 us; speedup 1.0000x reference)
//
#include <hip/hip_runtime.h>

#define NBOX 4000
#define NPAD 4096
#define BATCH 8
#define WPR 64          // 64-bit words per suppression row (padded stride)
#define MAXK 300

// Static device scratch (deterministic across replays: everything consulted is
// rewritten every call; rows >= nvalid are never read).
__device__ unsigned long long g_sup[BATCH][NBOX][WPR];   // ~16.4 MB
__device__ float4 g_sorted[BATCH][NPAD];                 // 512 KB
__device__ int g_nvalid[BATCH];

// ---------------------------------------------------------------------------
// Kernel 1: per-batch stable LSD radix sort (6 passes x 4 bits).
// Key k = 0x3F800000 - bits(fg) for valid boxes: valid => fg > 0.5 => bits(fg)
// in (0x3F000000, 0x3F800000) => k in (0, 0x800000) -- fits 24 bits, provably.
// Invalid/pad k = 0xFFFFFF sorts last. Ascending k == descending fg; stable
// radix with blocked per-thread ownership preserves original index order for
// ties (matches jnp.argsort stability).
// Pitch-17 LDS layout: element n lives at (n>>4)*17 + (n&15) -> the blocked
// 16-element per-thread reads hit 17-strided words = conflict-free.
// ---------------------------------------------------------------------------
#define SORT_T 256
#define EPT 16
#define HP 264                       // hist pitch (entries per digit row)
#define KIDX(n) ((((n) >> 4) * 17) + ((n) & 15))
#define KSZ (256 * 17)

__global__ __launch_bounds__(SORT_T) void sort_kernel(const float* __restrict__ props,
                                                      const float* __restrict__ scores) {
    const int b = blockIdx.x;
    const int tid = threadIdx.x;
    __shared__ unsigned int K0[KSZ], K1[KSZ];
    __shared__ unsigned short P0[KSZ], P1[KSZ];
    __shared__ unsigned short Hs[16 * HP];
    __shared__ unsigned int sWT[4];
    __shared__ int s_cnt;
    if (tid == 0) s_cnt = 0;
    __syncthreads();

    // Build keys + payloads (coalesced), count valid.
    int localc = 0;
    for (int n = tid; n < NPAD; n += SORT_T) {
        unsigned int k = 0xFFFFFFu;
        if (n < NBOX) {
            const float2 sc = *reinterpret_cast<const float2*>(scores + ((size_t)b * NBOX + n) * 2);
            const float4 p  = *reinterpret_cast<const float4*>(props  + ((size_t)b * NBOX + n) * 4);
            const float fg = sc.y;
            const float w = __fsub_rn(p.z, p.x);
            const float h = __fsub_rn(p.w, p.y);
            if ((fg > 0.5f) && (w >= 16.0f) && (h >= 16.0f)) {
                k = 0x3F800000u - __float_as_uint(fg);
                localc++;
            }
        }
        K0[KIDX(n)] = k;
        P0[KIDX(n)] = (unsigned short)n;
    }
    for (int off = 32; off > 0; off >>= 1) localc += __shfl_down(localc, off);
    if ((tid & 63) == 0) atomicAdd(&s_cnt, localc);

    unsigned int kr[EPT];
    unsigned short pr[EPT];

    for (int pass = 0; pass < 6; ++pass) {
        const int shift = pass * 4;
        const unsigned int*   ksrc = (pass & 1) ? K1 : K0;
        unsigned int*         kdst = (pass & 1) ? K0 : K1;
        const unsigned short* psrc = (pass & 1) ? P1 : P0;
        unsigned short*       pdst = (pass & 1) ? P0 : P1;

        // zero hist (also the barrier separating prev scatter from this pass)
        for (int hh = tid; hh < (16 * HP) / 2; hh += SORT_T)
            reinterpret_cast<unsigned int*>(Hs)[hh] = 0;
        __syncthreads();

        // load this thread's 16 elements once (regs survive the barriers)
        #pragma unroll
        for (int e = 0; e < EPT; ++e) {
            kr[e] = ksrc[tid * 17 + e];
            pr[e] = psrc[tid * 17 + e];
        }
        // count
        #pragma unroll
        for (int e = 0; e < EPT; ++e) {
            const unsigned int d = (kr[e] >> shift) & 15u;
            Hs[d * HP + tid]++;
        }
        __syncthreads();

        // exclusive scan over the 4096 (digit-major, then thread) counters
        {
            const int d  = tid >> 4;
            const int t0 = (tid & 15) * 16;
            unsigned short* row = &Hs[d * HP];
            unsigned int sum = 0;
            #pragma unroll
            for (int e = 0; e < 16; ++e) {
                const unsigned int v = row[t0 + e];
                row[t0 + e] = (unsigned short)sum;
                sum += v;
            }
            unsigned int x = sum;
            #pragma unroll
            for (int off = 1; off < 64; off <<= 1) {
                const unsigned int y = __shfl_up(x, off);
                if ((tid & 63) >= off) x += y;
            }
            const int wid = tid >> 6;
            if ((tid & 63) == 63) sWT[wid] = x;
            __syncthreads();
            unsigned int base = x - sum;        // exclusive within wave
            for (int w = 0; w < wid; ++w) base += sWT[w];
            #pragma unroll
            for (int e = 0; e < 16; ++e) row[t0 + e] += (unsigned short)base;
        }
        __syncthreads();

        // stable scatter
        #pragma unroll
        for (int e = 0; e < EPT; ++e) {
            const unsigned int d = (kr[e] >> shift) & 15u;
            const unsigned int pos = Hs[d * HP + tid]++;
            kdst[KIDX(pos)] = kr[e];
            pdst[KIDX(pos)] = pr[e];
        }
        __syncthreads();
    }

    const int nv = s_cnt;
    if (tid == 0) g_nvalid[b] = nv;
    for (int p = tid; p < NPAD; p += SORT_T) {
        if (p < nv) {
            const int idx = P0[KIDX(p)];
            g_sorted[b][p] = *reinterpret_cast<const float4*>(props + ((size_t)b * NBOX + idx) * 4);
        }
    }
}

// ---------------------------------------------------------------------------
// Kernel 2: suppression bitmask rows (triangular). Block = 64 lanes = row i.
// Starts at chunk c0 = i>>6 (bits j<=i are impossible anyway) -> 2x less work.
// fp32 ops match the reference bit-exactly (__f*_rn, correctly-rounded divide).
// ---------------------------------------------------------------------------
__global__ __launch_bounds__(64) void iou_kernel() {
    const int b = blockIdx.y;
    const int i = blockIdx.x;
    const int nv = g_nvalid[b];
    if (i >= nv) return;
    const int lane = threadIdx.x;
    const int c0 = i >> 6;
    const int W = (nv + 63) >> 6;

    const float4 bi = g_sorted[b][i];
    const float areai = __fmul_rn(__fsub_rn(bi.z, bi.x), __fsub_rn(bi.w, bi.y));

    unsigned long long myword = 0ull;
    for (int c = c0; c < W; ++c) {
        const int j = (c << 6) + lane;
        bool pred = false;
        if (j < nv && j > i) {
            const float4 bj = g_sorted[b][j];
            const float areaj = __fmul_rn(__fsub_rn(bj.z, bj.x), __fsub_rn(bj.w, bj.y));
            const float xi1 = fmaxf(bi.x, bj.x);
            const float yi1 = fmaxf(bi.y, bj.y);
            const float xi2 = fminf(bi.z, bj.z);
            const float yi2 = fminf(bi.w, bj.w);
            const float iw = fmaxf(__fsub_rn(xi2, xi1), 0.0f);
            const float ih = fmaxf(__fsub_rn(yi2, yi1), 0.0f);
            const float inter = __fmul_rn(iw, ih);
            const float uni = __fsub_rn(__fadd_rn(areai, areaj), inter);
            pred = (inter / uni) >= 0.5f;
        }
        const unsigned long long wd = __ballot(pred);
        if (lane == c) myword = wd;
    }
    g_sup[b][i][lane] = myword;   // lanes outside [c0,W) store 0
}

// ---------------------------------------------------------------------------
// Kernel 3: greedy scan with ffs-skip. One wave per batch. Lane w holds
// removed-word w. Per 64-row block: uniform `alive` mask; jump to next kept
// row via ctz; intra-block suppression via shfl of per-lane m (row's own
// block-column word, prefetched one block ahead); full-row OR loads ride off
// the serial chain. Early exit at 300 kept.
// ---------------------------------------------------------------------------
__global__ __launch_bounds__(64) void nms_kernel(float* __restrict__ out) {
    const int b = blockIdx.x;
    const int lane = threadIdx.x;
    int nv = g_nvalid[b];
    if (nv > NBOX) nv = NBOX;
    float4* outv = reinterpret_cast<float4*>(out) + (size_t)b * MAXK;
    const unsigned long long* supb = &g_sup[b][0][0];

    unsigned long long removed = 0ull;
    int kept = 0;
    unsigned long long m_cur = 0ull;
    if (lane < nv) m_cur = supb[(size_t)lane * WPR + 0];
    const int nblk = (nv + 63) >> 6;

    for (int blk = 0; blk < nblk && kept < MAXK; ++blk) {
        const int base = blk << 6;
        // prefetch next block's intra-block column
        unsigned long long m_nxt = 0ull;
        const int nbase = base + 64;
        if (nbase + lane < nv) m_nxt = supb[(size_t)(nbase + lane) * WPR + (blk + 1)];

        const unsigned long long wv = __shfl(removed, blk);   // uniform
        unsigned long long alive = ~wv;
        const int rem = nv - base;
        if (rem < 64) alive &= ((1ull << rem) - 1ull);

        while (alive && kept < MAXK) {
            const int l = __builtin_ctzll(alive);             // uniform
            const int i = base + l;
            const unsigned long long sl = __shfl(m_cur, l);   // row i's block word
            alive &= ~sl;
            alive &= ~(1ull << l);
            if (lane == 0) outv[kept] = g_sorted[b][i];
            kept++;
            removed |= supb[(size_t)i * WPR + lane];          // off-chain load
        }
        m_cur = m_nxt;
    }
    // zero-pad tail
    for (int s = kept + lane; s < MAXK; s += 64)
        outv[s] = make_float4(0.0f, 0.0f, 0.0f, 0.0f);
}

extern "C" void kernel_launch(void* const* d_in, const int* in_sizes, int n_in,
                              void* d_out, int out_size, void* d_ws, size_t ws_size,
                              hipStream_t stream) {
    const float* props  = (const float*)d_in[0];   // (8,4000,4) f32
    const float* scores = (const float*)d_in[1];   // (8,4000,2) f32
    float* out = (float*)d_out;                    // (8,300,4) f32

    sort_kernel<<<BATCH, SORT_T, 0, stream>>>(props, scores);
    iou_kernel<<<dim3(NBOX, BATCH), 64, 0, stream>>>();
    nms_kernel<<<BATCH, 64, 0, stream>>>(out);
}

// Round 3
// 99.897 us; speedup vs baseline: 1.5525x; 1.5525x over previous
//
#include <hip/hip_runtime.h>

#define NBOX 4000
#define NPAD 4096
#define BATCH 8
#define WPR 64          // 64-bit words per suppression row (padded stride)
#define MAXK 300

// Static device scratch (deterministic across replays: everything consulted is
// rewritten every call; rows >= nvalid are never read).
__device__ unsigned long long g_sup[BATCH][NBOX][WPR];   // ~16.4 MB
__device__ float4 g_sorted[BATCH][NPAD];                 // 512 KB
__device__ int g_nvalid[BATCH];

// ---------------------------------------------------------------------------
// Kernel 1: per-batch stable LSD radix sort (6 passes x 4 bits). (unchanged)
// Key k = 0x3F800000 - bits(fg): valid => fg > 0.5 => k in (0, 0x800000),
// fits 24 bits. Invalid/pad k = 0xFFFFFF sorts last. Stable blocked radix
// preserves original-index order for ties (matches jnp.argsort).
// ---------------------------------------------------------------------------
#define SORT_T 256
#define EPT 16
#define HP 264
#define KIDX(n) ((((n) >> 4) * 17) + ((n) & 15))
#define KSZ (256 * 17)

__global__ __launch_bounds__(SORT_T) void sort_kernel(const float* __restrict__ props,
                                                      const float* __restrict__ scores) {
    const int b = blockIdx.x;
    const int tid = threadIdx.x;
    __shared__ unsigned int K0[KSZ], K1[KSZ];
    __shared__ unsigned short P0[KSZ], P1[KSZ];
    __shared__ unsigned short Hs[16 * HP];
    __shared__ unsigned int sWT[4];
    __shared__ int s_cnt;
    if (tid == 0) s_cnt = 0;
    __syncthreads();

    int localc = 0;
    for (int n = tid; n < NPAD; n += SORT_T) {
        unsigned int k = 0xFFFFFFu;
        if (n < NBOX) {
            const float2 sc = *reinterpret_cast<const float2*>(scores + ((size_t)b * NBOX + n) * 2);
            const float4 p  = *reinterpret_cast<const float4*>(props  + ((size_t)b * NBOX + n) * 4);
            const float fg = sc.y;
            const float w = __fsub_rn(p.z, p.x);
            const float h = __fsub_rn(p.w, p.y);
            if ((fg > 0.5f) && (w >= 16.0f) && (h >= 16.0f)) {
                k = 0x3F800000u - __float_as_uint(fg);
                localc++;
            }
        }
        K0[KIDX(n)] = k;
        P0[KIDX(n)] = (unsigned short)n;
    }
    for (int off = 32; off > 0; off >>= 1) localc += __shfl_down(localc, off);
    if ((tid & 63) == 0) atomicAdd(&s_cnt, localc);

    unsigned int kr[EPT];
    unsigned short pr[EPT];

    for (int pass = 0; pass < 6; ++pass) {
        const int shift = pass * 4;
        const unsigned int*   ksrc = (pass & 1) ? K1 : K0;
        unsigned int*         kdst = (pass & 1) ? K0 : K1;
        const unsigned short* psrc = (pass & 1) ? P1 : P0;
        unsigned short*       pdst = (pass & 1) ? P0 : P1;

        for (int hh = tid; hh < (16 * HP) / 2; hh += SORT_T)
            reinterpret_cast<unsigned int*>(Hs)[hh] = 0;
        __syncthreads();

        #pragma unroll
        for (int e = 0; e < EPT; ++e) {
            kr[e] = ksrc[tid * 17 + e];
            pr[e] = psrc[tid * 17 + e];
        }
        #pragma unroll
        for (int e = 0; e < EPT; ++e) {
            const unsigned int d = (kr[e] >> shift) & 15u;
            Hs[d * HP + tid]++;
        }
        __syncthreads();

        {
            const int d  = tid >> 4;
            const int t0 = (tid & 15) * 16;
            unsigned short* row = &Hs[d * HP];
            unsigned int sum = 0;
            #pragma unroll
            for (int e = 0; e < 16; ++e) {
                const unsigned int v = row[t0 + e];
                row[t0 + e] = (unsigned short)sum;
                sum += v;
            }
            unsigned int x = sum;
            #pragma unroll
            for (int off = 1; off < 64; off <<= 1) {
                const unsigned int y = __shfl_up(x, off);
                if ((tid & 63) >= off) x += y;
            }
            const int wid = tid >> 6;
            if ((tid & 63) == 63) sWT[wid] = x;
            __syncthreads();
            unsigned int base = x - sum;
            for (int w = 0; w < wid; ++w) base += sWT[w];
            #pragma unroll
            for (int e = 0; e < 16; ++e) row[t0 + e] += (unsigned short)base;
        }
        __syncthreads();

        #pragma unroll
        for (int e = 0; e < EPT; ++e) {
            const unsigned int d = (kr[e] >> shift) & 15u;
            const unsigned int pos = Hs[d * HP + tid]++;
            kdst[KIDX(pos)] = kr[e];
            pdst[KIDX(pos)] = pr[e];
        }
        __syncthreads();
    }

    const int nv = s_cnt;
    if (tid == 0) g_nvalid[b] = nv;
    for (int p = tid; p < NPAD; p += SORT_T) {
        if (p < nv) {
            const int idx = P0[KIDX(p)];
            g_sorted[b][p] = *reinterpret_cast<const float4*>(props + ((size_t)b * NBOX + idx) * 4);
        }
    }
}

// ---------------------------------------------------------------------------
// Kernel 2: suppression bitmask rows (triangular). (unchanged)
// ---------------------------------------------------------------------------
__global__ __launch_bounds__(64) void iou_kernel() {
    const int b = blockIdx.y;
    const int i = blockIdx.x;
    const int nv = g_nvalid[b];
    if (i >= nv) return;
    const int lane = threadIdx.x;
    const int c0 = i >> 6;
    const int W = (nv + 63) >> 6;

    const float4 bi = g_sorted[b][i];
    const float areai = __fmul_rn(__fsub_rn(bi.z, bi.x), __fsub_rn(bi.w, bi.y));

    unsigned long long myword = 0ull;
    for (int c = c0; c < W; ++c) {
        const int j = (c << 6) + lane;
        bool pred = false;
        if (j < nv && j > i) {
            const float4 bj = g_sorted[b][j];
            const float areaj = __fmul_rn(__fsub_rn(bj.z, bj.x), __fsub_rn(bj.w, bj.y));
            const float xi1 = fmaxf(bi.x, bj.x);
            const float yi1 = fmaxf(bi.y, bj.y);
            const float xi2 = fminf(bi.z, bj.z);
            const float yi2 = fminf(bi.w, bj.w);
            const float iw = fmaxf(__fsub_rn(xi2, xi1), 0.0f);
            const float ih = fmaxf(__fsub_rn(yi2, yi1), 0.0f);
            const float inter = __fmul_rn(iw, ih);
            const float uni = __fsub_rn(__fadd_rn(areai, areaj), inter);
            pred = (inter / uni) >= 0.5f;
        }
        const unsigned long long wd = __ballot(pred);
        if (lane == c) myword = wd;
    }
    g_sup[b][i][lane] = myword;
}

// ---------------------------------------------------------------------------
// Kernel 3: greedy scan, one wave per batch. Per 64-row block:
//   (a) register-only serial phase determines the block's kept set from
//       m_cur (prefetched intra-block column) + wv — NO memory on the chain;
//       lane t records the t-th kept index in myIdx.
//   (b) lanes < m write output boxes in parallel (off-chain).
//   (c) batched OR: 16 NAMED u64 regs, 16 independent loads, ONE waitcnt,
//       OR-tree into removed  → one memory round trip per block instead of
//       one per kept row (the R2 119 µs bug).
// ---------------------------------------------------------------------------
__global__ __launch_bounds__(64) void nms_kernel(float* __restrict__ out) {
    const int b = blockIdx.x;
    const int lane = threadIdx.x;
    int nv = g_nvalid[b];
    if (nv > NBOX) nv = NBOX;
    float4* outv = reinterpret_cast<float4*>(out) + (size_t)b * MAXK;
    const unsigned long long* supb = &g_sup[b][0][0];

    unsigned long long removed = 0ull;
    int kept = 0;
    unsigned long long m_cur = 0ull;
    if (lane < nv) m_cur = supb[(size_t)lane * WPR + 0];
    const int nblk = (nv + 63) >> 6;

    for (int blk = 0; blk < nblk && kept < MAXK; ++blk) {
        const int base = blk << 6;
        // prefetch next block's intra-block column (hidden under this block)
        unsigned long long m_nxt = 0ull;
        const int nbase = base + 64;
        if (nbase + lane < nv) m_nxt = supb[(size_t)(nbase + lane) * WPR + (blk + 1)];

        const unsigned long long wv = __shfl(removed, blk);   // one vmcnt drain / block
        unsigned long long alive = ~wv;
        const int rem = nv - base;
        if (rem < 64) alive &= ((1ull << rem) - 1ull);

        // (a) register-only kept-set computation
        int m = 0;
        int myIdx = 0;
        while (alive && (kept + m) < MAXK) {
            const int l = __builtin_ctzll(alive);             // uniform
            const unsigned long long sl = __shfl(m_cur, l);
            alive &= ~sl;
            alive &= ~(1ull << l);
            if (lane == m) myIdx = base + l;
            ++m;
        }

        // (b) emit this block's outputs in parallel
        if (lane < m) outv[kept + lane] = g_sorted[b][myIdx];
        kept += m;

        // (c) batched OR of kept rows' suppression words
        if (kept < MAXK && blk + 1 < nblk) {
            for (int t = 0; t < m; t += 16) {
#define LDV(j) unsigned long long v##j = 0ull;                                   \
               {   const int tt = t + j;                                         \
                   const int it = __shfl(myIdx, tt);                             \
                   if (tt < m) v##j = supb[(size_t)it * WPR + lane];             }
                LDV(0)  LDV(1)  LDV(2)  LDV(3)
                LDV(4)  LDV(5)  LDV(6)  LDV(7)
                LDV(8)  LDV(9)  LDV(10) LDV(11)
                LDV(12) LDV(13) LDV(14) LDV(15)
#undef LDV
                removed |= (((v0 | v1) | (v2 | v3)) | ((v4 | v5) | (v6 | v7))) |
                           (((v8 | v9) | (v10 | v11)) | ((v12 | v13) | (v14 | v15)));
            }
        }
        m_cur = m_nxt;
    }

    // zero-pad tail
    for (int s = kept + lane; s < MAXK; s += 64)
        outv[s] = make_float4(0.0f, 0.0f, 0.0f, 0.0f);
}

extern "C" void kernel_launch(void* const* d_in, const int* in_sizes, int n_in,
                              void* d_out, int out_size, void* d_ws, size_t ws_size,
                              hipStream_t stream) {
    const float* props  = (const float*)d_in[0];   // (8,4000,4) f32
    const float* scores = (const float*)d_in[1];   // (8,4000,2) f32
    float* out = (float*)d_out;                    // (8,300,4) f32

    sort_kernel<<<BATCH, SORT_T, 0, stream>>>(props, scores);
    iou_kernel<<<dim3(NBOX, BATCH), 64, 0, stream>>>();
    nms_kernel<<<BATCH, 64, 0, stream>>>(out);
}

// Round 4
// 89.848 us; speedup vs baseline: 1.7262x; 1.1118x over previous
//
#include <hip/hip_runtime.h>

#define NBOX 4000
#define NPAD 4096
#define BATCH 8
#define WPR 64          // 64-bit words per suppression row (padded stride)
#define MAXK 300

// Static device scratch (deterministic across replays: everything consulted is
// rewritten every call; rows >= nvalid are never read).
__device__ unsigned long long g_sup[BATCH][NBOX][WPR];   // ~16.4 MB
__device__ float4 g_sorted[BATCH][NPAD];                 // 512 KB
__device__ int g_nvalid[BATCH];

// ---------------------------------------------------------------------------
// Kernel 1: per-batch stable LSD radix sort (6 passes x 4 bits). (unchanged)
// Key k = 0x3F800000 - bits(fg): valid => fg > 0.5 => k in (0, 0x800000),
// fits 24 bits. Invalid/pad k = 0xFFFFFF sorts last. Stable blocked radix
// preserves original-index order for ties (matches jnp.argsort).
// ---------------------------------------------------------------------------
#define SORT_T 256
#define EPT 16
#define HP 264
#define KIDX(n) ((((n) >> 4) * 17) + ((n) & 15))
#define KSZ (256 * 17)

__global__ __launch_bounds__(SORT_T) void sort_kernel(const float* __restrict__ props,
                                                      const float* __restrict__ scores) {
    const int b = blockIdx.x;
    const int tid = threadIdx.x;
    __shared__ unsigned int K0[KSZ], K1[KSZ];
    __shared__ unsigned short P0[KSZ], P1[KSZ];
    __shared__ unsigned short Hs[16 * HP];
    __shared__ unsigned int sWT[4];
    __shared__ int s_cnt;
    if (tid == 0) s_cnt = 0;
    __syncthreads();

    int localc = 0;
    for (int n = tid; n < NPAD; n += SORT_T) {
        unsigned int k = 0xFFFFFFu;
        if (n < NBOX) {
            const float2 sc = *reinterpret_cast<const float2*>(scores + ((size_t)b * NBOX + n) * 2);
            const float4 p  = *reinterpret_cast<const float4*>(props  + ((size_t)b * NBOX + n) * 4);
            const float fg = sc.y;
            const float w = __fsub_rn(p.z, p.x);
            const float h = __fsub_rn(p.w, p.y);
            if ((fg > 0.5f) && (w >= 16.0f) && (h >= 16.0f)) {
                k = 0x3F800000u - __float_as_uint(fg);
                localc++;
            }
        }
        K0[KIDX(n)] = k;
        P0[KIDX(n)] = (unsigned short)n;
    }
    for (int off = 32; off > 0; off >>= 1) localc += __shfl_down(localc, off);
    if ((tid & 63) == 0) atomicAdd(&s_cnt, localc);

    unsigned int kr[EPT];
    unsigned short pr[EPT];

    for (int pass = 0; pass < 6; ++pass) {
        const int shift = pass * 4;
        const unsigned int*   ksrc = (pass & 1) ? K1 : K0;
        unsigned int*         kdst = (pass & 1) ? K0 : K1;
        const unsigned short* psrc = (pass & 1) ? P1 : P0;
        unsigned short*       pdst = (pass & 1) ? P0 : P1;

        for (int hh = tid; hh < (16 * HP) / 2; hh += SORT_T)
            reinterpret_cast<unsigned int*>(Hs)[hh] = 0;
        __syncthreads();

        #pragma unroll
        for (int e = 0; e < EPT; ++e) {
            kr[e] = ksrc[tid * 17 + e];
            pr[e] = psrc[tid * 17 + e];
        }
        #pragma unroll
        for (int e = 0; e < EPT; ++e) {
            const unsigned int d = (kr[e] >> shift) & 15u;
            Hs[d * HP + tid]++;
        }
        __syncthreads();

        {
            const int d  = tid >> 4;
            const int t0 = (tid & 15) * 16;
            unsigned short* row = &Hs[d * HP];
            unsigned int sum = 0;
            #pragma unroll
            for (int e = 0; e < 16; ++e) {
                const unsigned int v = row[t0 + e];
                row[t0 + e] = (unsigned short)sum;
                sum += v;
            }
            unsigned int x = sum;
            #pragma unroll
            for (int off = 1; off < 64; off <<= 1) {
                const unsigned int y = __shfl_up(x, off);
                if ((tid & 63) >= off) x += y;
            }
            const int wid = tid >> 6;
            if ((tid & 63) == 63) sWT[wid] = x;
            __syncthreads();
            unsigned int base = x - sum;
            for (int w = 0; w < wid; ++w) base += sWT[w];
            #pragma unroll
            for (int e = 0; e < 16; ++e) row[t0 + e] += (unsigned short)base;
        }
        __syncthreads();

        #pragma unroll
        for (int e = 0; e < EPT; ++e) {
            const unsigned int d = (kr[e] >> shift) & 15u;
            const unsigned int pos = Hs[d * HP + tid]++;
            kdst[KIDX(pos)] = kr[e];
            pdst[KIDX(pos)] = pr[e];
        }
        __syncthreads();
    }

    const int nv = s_cnt;
    if (tid == 0) g_nvalid[b] = nv;
    for (int p = tid; p < NPAD; p += SORT_T) {
        if (p < nv) {
            const int idx = P0[KIDX(p)];
            g_sorted[b][p] = *reinterpret_cast<const float4*>(props + ((size_t)b * NBOX + idx) * 4);
        }
    }
}

// ---------------------------------------------------------------------------
// Kernel 2: suppression bitmask rows (triangular). (unchanged)
// ---------------------------------------------------------------------------
__global__ __launch_bounds__(64) void iou_kernel() {
    const int b = blockIdx.y;
    const int i = blockIdx.x;
    const int nv = g_nvalid[b];
    if (i >= nv) return;
    const int lane = threadIdx.x;
    const int c0 = i >> 6;
    const int W = (nv + 63) >> 6;

    const float4 bi = g_sorted[b][i];
    const float areai = __fmul_rn(__fsub_rn(bi.z, bi.x), __fsub_rn(bi.w, bi.y));

    unsigned long long myword = 0ull;
    for (int c = c0; c < W; ++c) {
        const int j = (c << 6) + lane;
        bool pred = false;
        if (j < nv && j > i) {
            const float4 bj = g_sorted[b][j];
            const float areaj = __fmul_rn(__fsub_rn(bj.z, bj.x), __fsub_rn(bj.w, bj.y));
            const float xi1 = fmaxf(bi.x, bj.x);
            const float yi1 = fmaxf(bi.y, bj.y);
            const float xi2 = fminf(bi.z, bj.z);
            const float yi2 = fminf(bi.w, bj.w);
            const float iw = fmaxf(__fsub_rn(xi2, xi1), 0.0f);
            const float ih = fmaxf(__fsub_rn(yi2, yi1), 0.0f);
            const float inter = __fmul_rn(iw, ih);
            const float uni = __fsub_rn(__fadd_rn(areai, areaj), inter);
            pred = (inter / uni) >= 0.5f;
        }
        const unsigned long long wd = __ballot(pred);
        if (lane == c) myword = wd;
    }
    g_sup[b][i][lane] = myword;
}

// ---------------------------------------------------------------------------
// Kernel 3: greedy scan, one wave per batch — SCALAR serial chain.
// alive / wv / per-row suppression words are wave-uniform, so the greedy loop
// runs entirely on the SALU: v_readlane (~4 cy) instead of ds_bpermute
// (~50 cy) per access. Per 64-row block the chain is:
//   readlane(removed,blk) -> scalar greedy (s_ff1 + 2x v_readlane + s_andn2
//   per kept row) -> 16 batched loads (ONE L3 round trip) -> OR tree.
// ---------------------------------------------------------------------------
__device__ __forceinline__ int rdl(int v, int l) {
    return __builtin_amdgcn_readlane(v, l);
}
__device__ __forceinline__ unsigned int rdlu(unsigned int v, int l) {
    return (unsigned int)__builtin_amdgcn_readlane((int)v, l);
}

__global__ __launch_bounds__(64) void nms_kernel(float* __restrict__ out) {
    const int b = blockIdx.x;
    const int lane = threadIdx.x;
    int nv = g_nvalid[b];
    if (nv > NBOX) nv = NBOX;
    float4* outv = reinterpret_cast<float4*>(out) + (size_t)b * MAXK;
    const unsigned long long* supb = &g_sup[b][0][0];

    // zero-fill output up-front (off the critical chain)
    for (int s = lane; s < MAXK; s += 64)
        outv[s] = make_float4(0.0f, 0.0f, 0.0f, 0.0f);

    unsigned long long removed = 0ull;     // lane w holds removed word w
    int kept = 0;
    unsigned long long m_cur = 0ull;       // sup[base+lane][blk] (intra-block col)
    if (lane < nv) m_cur = supb[(size_t)lane * WPR + 0];
    const int nblk = (nv + 63) >> 6;

    for (int blk = 0; blk < nblk && kept < MAXK; ++blk) {
        const int base = blk << 6;
        // prefetch next block's intra-block column (off-chain)
        unsigned long long m_nxt = 0ull;
        const int nbase = base + 64;
        if (nbase + lane < nv) m_nxt = supb[(size_t)(nbase + lane) * WPR + (blk + 1)];

        // scalar incoming-suppression word for this block
        const unsigned int wv_lo = rdlu((unsigned int)removed, blk);
        const unsigned int wv_hi = rdlu((unsigned int)(removed >> 32), blk);
        unsigned long long aliveU = ~(((unsigned long long)wv_hi << 32) | wv_lo);
        const int rem = nv - base;
        if (rem < 64) aliveU &= ((1ull << rem) - 1ull);

        unsigned int alive_lo = (unsigned int)__builtin_amdgcn_readfirstlane((int)(unsigned int)aliveU);
        unsigned int alive_hi = (unsigned int)__builtin_amdgcn_readfirstlane((int)(unsigned int)(aliveU >> 32));

        const unsigned int mc_lo = (unsigned int)m_cur;
        const unsigned int mc_hi = (unsigned int)(m_cur >> 32);

        // (a) scalar greedy over this block
        int m = 0;
        int myIdx = 0;                      // lane t gets the t-th kept index
        const int capm = MAXK - kept;
        while ((alive_lo | alive_hi) != 0u && m < capm) {
            const int l = alive_lo ? __builtin_ctz(alive_lo) : 32 + __builtin_ctz(alive_hi);
            const unsigned int sl_lo = rdlu(mc_lo, l);
            const unsigned int sl_hi = rdlu(mc_hi, l);
            unsigned long long clr = (((unsigned long long)sl_hi << 32) | sl_lo) | (1ull << l);
            alive_lo &= ~(unsigned int)clr;
            alive_hi &= ~(unsigned int)(clr >> 32);
            if (lane == m) myIdx = base + l;
            ++m;
        }

        // (c) batched OR of kept rows' suppression words — issue loads FIRST
        //     (16 independent loads, one waitcnt, OR tree). Duplicate clamped
        //     loads are harmless (OR of a kept row twice is idempotent).
        if (m > 0) {
            if (kept + m < MAXK && blk + 1 < nblk) {
                for (int t = 0; t < m; t += 16) {
#define LDV(j) unsigned long long v##j; {                                        \
                   int tt = t + j; if (tt >= m) tt = m - 1;                      \
                   const int it = rdl(myIdx, tt);                                \
                   v##j = supb[(size_t)it * WPR + lane];                         }
                    LDV(0)  LDV(1)  LDV(2)  LDV(3)
                    LDV(4)  LDV(5)  LDV(6)  LDV(7)
                    LDV(8)  LDV(9)  LDV(10) LDV(11)
                    LDV(12) LDV(13) LDV(14) LDV(15)
#undef LDV
                    removed |= (((v0 | v1) | (v2 | v3)) | ((v4 | v5) | (v6 | v7))) |
                               (((v8 | v9) | (v10 | v11)) | ((v12 | v13) | (v14 | v15)));
                }
            }
            // (b) emit this block's outputs (off-chain)
            if (lane < m) outv[kept + lane] = g_sorted[b][myIdx];
            kept += m;
        }
        m_cur = m_nxt;
    }
}

extern "C" void kernel_launch(void* const* d_in, const int* in_sizes, int n_in,
                              void* d_out, int out_size, void* d_ws, size_t ws_size,
                              hipStream_t stream) {
    const float* props  = (const float*)d_in[0];   // (8,4000,4) f32
    const float* scores = (const float*)d_in[1];   // (8,4000,2) f32
    float* out = (float*)d_out;                    // (8,300,4) f32

    sort_kernel<<<BATCH, SORT_T, 0, stream>>>(props, scores);
    iou_kernel<<<dim3(NBOX, BATCH), 64, 0, stream>>>();
    nms_kernel<<<BATCH, 64, 0, stream>>>(out);
}